// Round 1
// baseline (247.344 us; speedup 1.0000x reference)
//
#include <hip/hip_runtime.h>
#include <hip/hip_bf16.h>

#define NT 4096
#define DIM 1024
#define NH 16
#define HD 64

typedef __attribute__((ext_vector_type(8))) short bf16x8;
typedef __attribute__((ext_vector_type(4))) float f32x4;

__device__ __forceinline__ unsigned short f2b(float f) {
  union { float f; unsigned u; } v; v.f = f;
  unsigned r = v.u + 0x7fffu + ((v.u >> 16) & 1u);
  return (unsigned short)(r >> 16);
}

// ---------- 1) fp32 -> bf16 elementwise ----------
__global__ void k_cvt(const float4* __restrict__ src, ushort4* __restrict__ dst, int n4) {
  int i = blockIdx.x * blockDim.x + threadIdx.x;
  if (i >= n4) return;
  float4 v = src[i];
  ushort4 o;
  o.x = f2b(v.x); o.y = f2b(v.y); o.z = f2b(v.z); o.w = f2b(v.w);
  dst[i] = o;
}

// ---------- 2) transpose fp32 [1024][S] (cols [0,N)) -> bf16 [N][1024] ----------
__global__ __launch_bounds__(256) void k_trans_w(const float* __restrict__ src, int S,
                                                 unsigned short* __restrict__ dst, int Kdim) {
  __shared__ float tile[32][33];
  int j0 = blockIdx.x * 32, k0 = blockIdx.y * 32;
  int t = threadIdx.x;
  int c = t & 31, rq = t >> 5;
#pragma unroll
  for (int i = 0; i < 4; i++) {
    int r = rq + i * 8;
    tile[r][c] = src[(size_t)(k0 + r) * S + j0 + c];
  }
  __syncthreads();
#pragma unroll
  for (int i = 0; i < 4; i++) {
    int jr = rq + i * 8;
    dst[(size_t)(j0 + jr) * Kdim + k0 + c] = f2b(tile[c][jr]);
  }
}

// ---------- 3) bf16 MFMA GEMM, 128x128 tile, B given transposed [N][K] ----------
// EPI 0: scatter epilogue -> qh (scaled 1/8) for j<1024, krm for j>=1024
// EPI 1: fp32 out + bias
template <int EPI>
__global__ __launch_bounds__(256) void k_gemm(const unsigned short* __restrict__ A,
                                              const unsigned short* __restrict__ Bt,
                                              unsigned short* __restrict__ qh,
                                              unsigned short* __restrict__ krm,
                                              float* __restrict__ cout,
                                              const float* __restrict__ bias) {
  __shared__ unsigned short As[128][40];
  __shared__ unsigned short Bs[128][40];
  const int K = 1024;
  int m0 = blockIdx.y * 128, n0 = blockIdx.x * 128;
  int t = threadIdx.x;
  int w = t >> 6, l = t & 63;
  int wr = w >> 1, wc = w & 1;
  int lq = l & 15, lg = l >> 4;
  f32x4 zero = {0.f, 0.f, 0.f, 0.f};
  f32x4 acc[4][4];
#pragma unroll
  for (int i = 0; i < 4; i++)
#pragma unroll
    for (int j = 0; j < 4; j++) acc[i][j] = zero;

  for (int k0 = 0; k0 < K; k0 += 32) {
#pragma unroll
    for (int s = 0; s < 2; s++) {
      int slot = t + s * 256;
      int r = slot >> 2, c8 = (slot & 3) * 8;
      *reinterpret_cast<bf16x8*>(&As[r][c8]) =
          *reinterpret_cast<const bf16x8*>(A + (size_t)(m0 + r) * K + k0 + c8);
      *reinterpret_cast<bf16x8*>(&Bs[r][c8]) =
          *reinterpret_cast<const bf16x8*>(Bt + (size_t)(n0 + r) * K + k0 + c8);
    }
    __syncthreads();
    bf16x8 af[4], bf[4];
#pragma unroll
    for (int mi = 0; mi < 4; mi++)
      af[mi] = *reinterpret_cast<bf16x8*>(&As[wr * 64 + mi * 16 + lq][lg * 8]);
#pragma unroll
    for (int ni = 0; ni < 4; ni++)
      bf[ni] = *reinterpret_cast<bf16x8*>(&Bs[wc * 64 + ni * 16 + lq][lg * 8]);
#pragma unroll
    for (int mi = 0; mi < 4; mi++)
#pragma unroll
      for (int ni = 0; ni < 4; ni++)
        acc[mi][ni] =
            __builtin_amdgcn_mfma_f32_16x16x32_bf16(af[mi], bf[ni], acc[mi][ni], 0, 0, 0);
    __syncthreads();
  }
#pragma unroll
  for (int mi = 0; mi < 4; mi++) {
#pragma unroll
    for (int ni = 0; ni < 4; ni++) {
      int j = n0 + wc * 64 + ni * 16 + lq;
#pragma unroll
      for (int r = 0; r < 4; r++) {
        int row = m0 + wr * 64 + mi * 16 + lg * 4 + r;
        float v = acc[mi][ni][r];
        if (EPI == 0) {
          if (j < DIM) {
            qh[((size_t)(j >> 6) << 18) + (size_t)row * HD + (j & 63)] = f2b(v * 0.125f);
          } else {
            int jj = j - DIM;
            krm[((size_t)(jj >> 6) << 18) + (size_t)row * HD + (jj & 63)] = f2b(v);
          }
        } else {
          cout[(size_t)row * DIM + j] = v + bias[j];
        }
      }
    }
  }
}

// ---------- 4) per-head transpose K[h][n][64] -> Kt[h][64][4096] ----------
__global__ __launch_bounds__(256) void k_transK(const unsigned short* __restrict__ krm,
                                                unsigned short* __restrict__ kt) {
  __shared__ unsigned short tile[64][72];
  int h = blockIdx.y, n0 = blockIdx.x * 64;
  int t = threadIdx.x;
  const unsigned short* src = krm + (size_t)h * NT * HD;
#pragma unroll
  for (int s = 0; s < 2; s++) {
    int slot = t + s * 256;
    int r = slot >> 3, c8 = (slot & 7) * 8;
    *reinterpret_cast<bf16x8*>(&tile[r][c8]) =
        *reinterpret_cast<const bf16x8*>(src + (size_t)(n0 + r) * HD + c8);
  }
  __syncthreads();
  unsigned short* dst = kt + (size_t)h * HD * NT;
#pragma unroll
  for (int s = 0; s < 2; s++) {
    int slot = t + s * 256;
    int dd = slot & 63, c8 = (slot >> 6) * 8;
    bf16x8 vv;
#pragma unroll
    for (int i = 0; i < 8; i++) vv[i] = (short)tile[c8 + i][dd];
    *reinterpret_cast<bf16x8*>(dst + (size_t)dd * NT + n0 + c8) = vv;
  }
}

// ---------- 5) flash attention, V := K, swapped QK^T ----------
__global__ __launch_bounds__(256) void k_attn(const unsigned short* __restrict__ qh,
                                              const unsigned short* __restrict__ krm,
                                              const unsigned short* __restrict__ kt,
                                              unsigned short* __restrict__ att) {
  __shared__ unsigned short Ka[64][72];    // K tile row-major [kv][d]  (A of S')
  __shared__ unsigned short Ktl[64][72];   // K tile transposed [d][kv] (B of PV)
  __shared__ unsigned short Pl[4][16][72]; // per-wave P [q][kv]
  int h = blockIdx.y, q0 = blockIdx.x * 64;
  int t = threadIdx.x, w = t >> 6, l = t & 63;
  int lq = l & 15, lg = l >> 4;
  const unsigned short* Qb = qh + (size_t)h * NT * HD;
  const unsigned short* Kb = krm + (size_t)h * NT * HD;
  const unsigned short* Tb = kt + (size_t)h * HD * NT;
  int qrow = q0 + w * 16 + lq;
  bf16x8 qf0 = *reinterpret_cast<const bf16x8*>(Qb + (size_t)qrow * HD + lg * 8);
  bf16x8 qf1 = *reinterpret_cast<const bf16x8*>(Qb + (size_t)qrow * HD + 32 + lg * 8);
  f32x4 zero = {0.f, 0.f, 0.f, 0.f};
  f32x4 o[4];
#pragma unroll
  for (int df = 0; df < 4; df++) o[df] = zero;
  float m_run = -1.0e30f, l_run = 0.f;

  for (int kv0 = 0; kv0 < NT; kv0 += 64) {
#pragma unroll
    for (int s = 0; s < 2; s++) {
      int slot = t + s * 256;
      int r = slot >> 3, c8 = (slot & 7) * 8;
      *reinterpret_cast<bf16x8*>(&Ka[r][c8]) =
          *reinterpret_cast<const bf16x8*>(Kb + (size_t)(kv0 + r) * HD + c8);
      *reinterpret_cast<bf16x8*>(&Ktl[r][c8]) =
          *reinterpret_cast<const bf16x8*>(Tb + (size_t)r * NT + kv0 + c8);
    }
    __syncthreads();
    // S'[kv][q] = K · Qs^T ; lane holds q=lq, kv = 16f + 4*lg + r
    f32x4 sc[4];
#pragma unroll
    for (int f = 0; f < 4; f++) {
      bf16x8 ka0 = *reinterpret_cast<bf16x8*>(&Ka[f * 16 + lq][lg * 8]);
      bf16x8 ka1 = *reinterpret_cast<bf16x8*>(&Ka[f * 16 + lq][32 + lg * 8]);
      f32x4 z = zero;
      z = __builtin_amdgcn_mfma_f32_16x16x32_bf16(ka0, qf0, z, 0, 0, 0);
      sc[f] = __builtin_amdgcn_mfma_f32_16x16x32_bf16(ka1, qf1, z, 0, 0, 0);
    }
    // online softmax over kv for row q=lq
    float pm = -1.0e30f;
#pragma unroll
    for (int f = 0; f < 4; f++)
#pragma unroll
      for (int r = 0; r < 4; r++) pm = fmaxf(pm, sc[f][r]);
    pm = fmaxf(pm, __shfl_xor(pm, 16));
    pm = fmaxf(pm, __shfl_xor(pm, 32));
    float newm = fmaxf(m_run, pm);
    float psum = 0.f;
#pragma unroll
    for (int f = 0; f < 4; f++)
#pragma unroll
      for (int r = 0; r < 4; r++) {
        float e = __expf(sc[f][r] - newm);
        sc[f][r] = e;
        psum += e;
      }
    psum += __shfl_xor(psum, 16);
    psum += __shfl_xor(psum, 32);
    float alpha = __expf(m_run - newm);
    l_run = l_run * alpha + psum;
    m_run = newm;
    // rescale O rows (row q_loc = 4*lg + r; stats live at lane q_loc)
#pragma unroll
    for (int r = 0; r < 4; r++) {
      float ar = __shfl(alpha, lg * 4 + r);
#pragma unroll
      for (int df = 0; df < 4; df++) o[df][r] *= ar;
    }
    // P -> LDS as [q][kv] bf16 (per-wave region, no barrier needed)
#pragma unroll
    for (int f = 0; f < 4; f++) {
      unsigned p01 = (unsigned)f2b(sc[f][0]) | ((unsigned)f2b(sc[f][1]) << 16);
      unsigned p23 = (unsigned)f2b(sc[f][2]) | ((unsigned)f2b(sc[f][3]) << 16);
      unsigned* pd = reinterpret_cast<unsigned*>(&Pl[w][lq][f * 16 + lg * 4]);
      pd[0] = p01;
      pd[1] = p23;
    }
    asm volatile("s_waitcnt lgkmcnt(0)" ::: "memory");
    __builtin_amdgcn_sched_barrier(0);
    bf16x8 pf0 = *reinterpret_cast<bf16x8*>(&Pl[w][lq][lg * 8]);
    bf16x8 pf1 = *reinterpret_cast<bf16x8*>(&Pl[w][lq][32 + lg * 8]);
    // O[q][d] += P · V  (V := K, B-operand from transposed tile)
#pragma unroll
    for (int df = 0; df < 4; df++) {
      bf16x8 v0 = *reinterpret_cast<bf16x8*>(&Ktl[df * 16 + lq][lg * 8]);
      bf16x8 v1 = *reinterpret_cast<bf16x8*>(&Ktl[df * 16 + lq][32 + lg * 8]);
      o[df] = __builtin_amdgcn_mfma_f32_16x16x32_bf16(pf0, v0, o[df], 0, 0, 0);
      o[df] = __builtin_amdgcn_mfma_f32_16x16x32_bf16(pf1, v1, o[df], 0, 0, 0);
    }
    __syncthreads();
  }
  float linv = 1.0f / l_run;
#pragma unroll
  for (int r = 0; r < 4; r++) {
    float lr = __shfl(linv, lg * 4 + r);
    int row = q0 + w * 16 + lg * 4 + r;
#pragma unroll
    for (int df = 0; df < 4; df++) {
      att[(size_t)row * DIM + h * HD + df * 16 + lq] = f2b(o[df][r] * lr);
    }
  }
}

extern "C" void kernel_launch(void* const* d_in, const int* in_sizes, int n_in,
                              void* d_out, int out_size, void* d_ws, size_t ws_size,
                              hipStream_t stream) {
  const float* x = (const float*)d_in[0];
  const float* w_qkv = (const float*)d_in[1];
  const float* w_out = (const float*)d_in[2];
  const float* b_out = (const float*)d_in[3];
  float* out = (float*)d_out;

  char* ws = (char*)d_ws;
  unsigned short* xb   = (unsigned short*)(ws);              // [4096][1024]   8 MB
  unsigned short* wqkT = (unsigned short*)(ws + 8388608);    // [2048][1024]   4 MB
  unsigned short* woT  = (unsigned short*)(ws + 12582912);   // [1024][1024]   2 MB
  unsigned short* qhb  = (unsigned short*)(ws + 14680064);   // [16][4096][64] 8 MB (q * 1/8)
  unsigned short* krm  = (unsigned short*)(ws + 23068672);   // [16][4096][64] 8 MB
  unsigned short* ktb  = (unsigned short*)(ws + 31457280);   // [16][64][4096] 8 MB
  unsigned short* attb = (unsigned short*)(ws + 39845888);   // [4096][1024]   8 MB

  k_cvt<<<(NT * DIM / 4 + 255) / 256, 256, 0, stream>>>((const float4*)x, (ushort4*)xb,
                                                        NT * DIM / 4);
  dim3 g1(2048 / 32, 1024 / 32);
  k_trans_w<<<g1, 256, 0, stream>>>(w_qkv, 3 * DIM, wqkT, DIM);
  dim3 g2(1024 / 32, 1024 / 32);
  k_trans_w<<<g2, 256, 0, stream>>>(w_out, DIM, woT, DIM);
  dim3 g3(2048 / 128, NT / 128);
  k_gemm<0><<<g3, 256, 0, stream>>>(xb, wqkT, qhb, krm, nullptr, nullptr);
  dim3 g4(NT / 64, NH);
  k_transK<<<g4, 256, 0, stream>>>(krm, ktb);
  k_attn<<<g4, 256, 0, stream>>>(qhb, krm, ktb, attb);
  dim3 g5(DIM / 128, NT / 128);
  k_gemm<1><<<g5, 256, 0, stream>>>(attb, woT, nullptr, nullptr, out, b_out);
}

// Round 2
// 210.020 us; speedup vs baseline: 1.1777x; 1.1777x over previous
//
#include <hip/hip_runtime.h>
#include <hip/hip_bf16.h>

#define NT 4096
#define DIM 1024
#define NH 16
#define HD 64

typedef __attribute__((ext_vector_type(8))) short bf16x8;
typedef __attribute__((ext_vector_type(4))) float f32x4;
typedef __attribute__((ext_vector_type(16))) float f32x16;

__device__ __forceinline__ unsigned short f2b(float f) {
  union { float f; unsigned u; } v; v.f = f;
  unsigned r = v.u + 0x7fffu + ((v.u >> 16) & 1u);
  return (unsigned short)(r >> 16);
}

// ---------- 1) fp32 -> bf16 elementwise ----------
__global__ void k_cvt(const float4* __restrict__ src, ushort4* __restrict__ dst, int n4) {
  int i = blockIdx.x * blockDim.x + threadIdx.x;
  if (i >= n4) return;
  float4 v = src[i];
  ushort4 o;
  o.x = f2b(v.x); o.y = f2b(v.y); o.z = f2b(v.z); o.w = f2b(v.w);
  dst[i] = o;
}

// ---------- 2) transpose fp32 [1024][S] (cols [0,N)) -> bf16 [N][1024] ----------
__global__ __launch_bounds__(256) void k_trans_w(const float* __restrict__ src, int S,
                                                 unsigned short* __restrict__ dst, int Kdim) {
  __shared__ float tile[32][33];
  int j0 = blockIdx.x * 32, k0 = blockIdx.y * 32;
  int t = threadIdx.x;
  int c = t & 31, rq = t >> 5;
#pragma unroll
  for (int i = 0; i < 4; i++) {
    int r = rq + i * 8;
    tile[r][c] = src[(size_t)(k0 + r) * S + j0 + c];
  }
  __syncthreads();
#pragma unroll
  for (int i = 0; i < 4; i++) {
    int jr = rq + i * 8;
    dst[(size_t)(j0 + jr) * Kdim + k0 + c] = f2b(tile[c][jr]);
  }
}

// ---------- 3) bf16 MFMA GEMM, 128x128 tile, B given transposed [N][K] ----------
// EPI 0: scatter epilogue -> qh (scaled 0.125*log2e) for j<1024, krm for j>=1024
// EPI 1: fp32 out + bias
template <int EPI>
__global__ __launch_bounds__(256) void k_gemm(const unsigned short* __restrict__ A,
                                              const unsigned short* __restrict__ Bt,
                                              unsigned short* __restrict__ qh,
                                              unsigned short* __restrict__ krm,
                                              float* __restrict__ cout,
                                              const float* __restrict__ bias) {
  __shared__ unsigned short As[128][40];
  __shared__ unsigned short Bs[128][40];
  const int K = 1024;
  int m0 = blockIdx.y * 128, n0 = blockIdx.x * 128;
  int t = threadIdx.x;
  int w = t >> 6, l = t & 63;
  int wr = w >> 1, wc = w & 1;
  int lq = l & 15, lg = l >> 4;
  f32x4 zero = {0.f, 0.f, 0.f, 0.f};
  f32x4 acc[4][4];
#pragma unroll
  for (int i = 0; i < 4; i++)
#pragma unroll
    for (int j = 0; j < 4; j++) acc[i][j] = zero;

  for (int k0 = 0; k0 < K; k0 += 32) {
#pragma unroll
    for (int s = 0; s < 2; s++) {
      int slot = t + s * 256;
      int r = slot >> 2, c8 = (slot & 3) * 8;
      *reinterpret_cast<bf16x8*>(&As[r][c8]) =
          *reinterpret_cast<const bf16x8*>(A + (size_t)(m0 + r) * K + k0 + c8);
      *reinterpret_cast<bf16x8*>(&Bs[r][c8]) =
          *reinterpret_cast<const bf16x8*>(Bt + (size_t)(n0 + r) * K + k0 + c8);
    }
    __syncthreads();
    bf16x8 af[4], bf[4];
#pragma unroll
    for (int mi = 0; mi < 4; mi++)
      af[mi] = *reinterpret_cast<bf16x8*>(&As[wr * 64 + mi * 16 + lq][lg * 8]);
#pragma unroll
    for (int ni = 0; ni < 4; ni++)
      bf[ni] = *reinterpret_cast<bf16x8*>(&Bs[wc * 64 + ni * 16 + lq][lg * 8]);
#pragma unroll
    for (int mi = 0; mi < 4; mi++)
#pragma unroll
      for (int ni = 0; ni < 4; ni++)
        acc[mi][ni] =
            __builtin_amdgcn_mfma_f32_16x16x32_bf16(af[mi], bf[ni], acc[mi][ni], 0, 0, 0);
    __syncthreads();
  }
#pragma unroll
  for (int mi = 0; mi < 4; mi++) {
#pragma unroll
    for (int ni = 0; ni < 4; ni++) {
      int j = n0 + wc * 64 + ni * 16 + lq;
#pragma unroll
      for (int r = 0; r < 4; r++) {
        int row = m0 + wr * 64 + mi * 16 + lg * 4 + r;
        float v = acc[mi][ni][r];
        if (EPI == 0) {
          if (j < DIM) {
            // fold 1/8 and log2(e): softmax later uses exp2 directly
            qh[((size_t)(j >> 6) << 18) + (size_t)row * HD + (j & 63)] =
                f2b(v * 0.18033688011112042f);
          } else {
            int jj = j - DIM;
            krm[((size_t)(jj >> 6) << 18) + (size_t)row * HD + (jj & 63)] = f2b(v);
          }
        } else {
          cout[(size_t)row * DIM + j] = v + bias[j];
        }
      }
    }
  }
}

// ---------- 4) per-head transpose K[h][n][64] -> Kt[h][64][4096] ----------
__global__ __launch_bounds__(256) void k_transK(const unsigned short* __restrict__ krm,
                                                unsigned short* __restrict__ kt) {
  __shared__ unsigned short tile[64][72];
  int h = blockIdx.y, n0 = blockIdx.x * 64;
  int t = threadIdx.x;
  const unsigned short* src = krm + (size_t)h * NT * HD;
#pragma unroll
  for (int s = 0; s < 2; s++) {
    int slot = t + s * 256;
    int r = slot >> 3, c8 = (slot & 7) * 8;
    *reinterpret_cast<bf16x8*>(&tile[r][c8]) =
        *reinterpret_cast<const bf16x8*>(src + (size_t)(n0 + r) * HD + c8);
  }
  __syncthreads();
  unsigned short* dst = kt + (size_t)h * HD * NT;
#pragma unroll
  for (int s = 0; s < 2; s++) {
    int slot = t + s * 256;
    int dd = slot & 63, c8 = (slot >> 6) * 8;
    bf16x8 vv;
#pragma unroll
    for (int i = 0; i < 8; i++) vv[i] = (short)tile[c8 + i][dd];
    *reinterpret_cast<bf16x8*>(dst + (size_t)dd * NT + n0 + c8) = vv;
  }
}

// ---------- 5) flash attention, V := K, 32x32 MFMA, in-register P ----------
// 4 waves x 32 q-rows = 128 q/block; KVBLK=64; scores already in log2 domain.
__global__ __launch_bounds__(256) void k_attn(const unsigned short* __restrict__ qh,
                                              const unsigned short* __restrict__ krm,
                                              const unsigned short* __restrict__ kt,
                                              unsigned short* __restrict__ att) {
  __shared__ __align__(16) unsigned char sbuf[2][16384];  // [Ka 8K | Ktl 8K] x dbuf

  // XCD swizzle: 512 blocks, xcd = hw&7 handles heads {2*xcd, 2*xcd+1}
  int hw = blockIdx.x;
  int xcd = hw & 7, idx = hw >> 3;
  int h = xcd * 2 + (idx >> 5);
  int q0 = (idx & 31) * 128;

  int t = threadIdx.x, w = t >> 6, l = t & 63;
  int lq = l & 31, hi = l >> 5;
  const unsigned char* Kb = (const unsigned char*)(krm + (size_t)h * NT * HD);
  const unsigned char* Tb = (const unsigned char*)(kt + (size_t)h * HD * NT);
  const unsigned short* Qb = qh + (size_t)h * NT * HD;

  int qrow = q0 + w * 32 + lq;
  bf16x8 qf[4];
#pragma unroll
  for (int ds = 0; ds < 4; ds++)
    qf[ds] = *reinterpret_cast<const bf16x8*>(Qb + (size_t)qrow * HD + ds * 16 + hi * 8);

  // precomputed swizzled LDS read offsets (tile-invariant)
  int swz = (lq & 7) << 4;
  int qk_off[2][4], pv_off[2][4];
#pragma unroll
  for (int kb2 = 0; kb2 < 2; kb2++)
#pragma unroll
    for (int ds = 0; ds < 4; ds++)
      qk_off[kb2][ds] = ((kb2 * 32 + lq) << 7) + ((32 * ds + 16 * hi) ^ swz);
#pragma unroll
  for (int dblk = 0; dblk < 2; dblk++)
#pragma unroll
    for (int kb = 0; kb < 4; kb++)
      pv_off[dblk][kb] = 8192 + ((dblk * 32 + lq) << 7) + ((32 * kb + 16 * hi) ^ swz);

  f32x16 o0, o1;
#pragma unroll
  for (int r = 0; r < 16; r++) { o0[r] = 0.f; o1[r] = 0.f; }
  float m_run = -3.0e38f, l_run = 0.f;

  auto STAGE = [&](int b, int kv0) {
    unsigned char* base = &sbuf[b][0];
#pragma unroll
    for (int i = 0; i < 4; i++) {
      int c = w * 4 + i;                 // chunk 0..15, wave-uniform
      int o = c * 1024 + l * 16;         // this lane's dest byte offset
      const unsigned char* g;
      if (c < 8) {                       // Ka region: row-major K tile [64][128B]
        int row = o >> 7;
        int so = (o ^ ((row & 7) << 4)) & 127;   // inverse-swizzled source col
        g = Kb + (size_t)(kv0 + row) * 128 + so;
      } else {                           // Ktl region: Kt tile [64 d][128B kv]
        int oo = o - 8192;
        int row = oo >> 7;
        int so = (oo ^ ((row & 7) << 4)) & 127;
        g = Tb + (size_t)row * 8192 + (size_t)kv0 * 2 + so;
      }
      __builtin_amdgcn_global_load_lds(
          (const __attribute__((address_space(1))) unsigned int*)g,
          (__attribute__((address_space(3))) unsigned int*)(base + c * 1024), 16, 0, 0);
    }
  };

  STAGE(0, 0);
  __syncthreads();

  for (int tile = 0; tile < 64; tile++) {
    int cur = tile & 1;
    if (tile < 63) STAGE(cur ^ 1, (tile + 1) * 64);
    const unsigned char* KaB = &sbuf[cur][0];

    // ---- QK^T (swapped): S'[kv][q], lane holds q=lq, kv rows per C-layout ----
    f32x16 s0, s1;
#pragma unroll
    for (int r = 0; r < 16; r++) { s0[r] = 0.f; s1[r] = 0.f; }
#pragma unroll
    for (int ds = 0; ds < 4; ds++) {
      bf16x8 a0 = *reinterpret_cast<const bf16x8*>(KaB + qk_off[0][ds]);
      bf16x8 a1 = *reinterpret_cast<const bf16x8*>(KaB + qk_off[1][ds]);
      s0 = __builtin_amdgcn_mfma_f32_32x32x16_bf16(a0, qf[ds], s0, 0, 0, 0);
      s1 = __builtin_amdgcn_mfma_f32_32x32x16_bf16(a1, qf[ds], s1, 0, 0, 0);
    }

    // ---- online softmax (log2 domain), full row in-lane ----
    float pm = -3.0e38f;
#pragma unroll
    for (int r = 0; r < 16; r++) pm = fmaxf(pm, fmaxf(s0[r], s1[r]));
    pm = fmaxf(pm, __shfl_xor(pm, 32));
    if (__any(pm > m_run + 8.0f)) {
      float newm = fmaxf(m_run, pm);
      float al = exp2f(m_run - newm);
#pragma unroll
      for (int r = 0; r < 16; r++) {
        float av = __shfl(al, (r & 3) + 8 * (r >> 2) + 4 * hi);
        o0[r] *= av;
        o1[r] *= av;
      }
      l_run *= al;
      m_run = newm;
    }
    float p0[16], p1[16];
    float ps = 0.f;
#pragma unroll
    for (int r = 0; r < 16; r++) { p0[r] = exp2f(s0[r] - m_run); ps += p0[r]; }
#pragma unroll
    for (int r = 0; r < 16; r++) { p1[r] = exp2f(s1[r] - m_run); ps += p1[r]; }
    ps += __shfl_xor(ps, 32);
    l_run += ps;

    // ---- P -> bf16 PV A-fragments, fully in-register (cvt_pk + permlane32_swap) ----
    unsigned pk0[8], pk1[8];
#pragma unroll
    for (int i = 0; i < 8; i++) {
      asm("v_cvt_pk_bf16_f32 %0, %1, %2" : "=v"(pk0[i]) : "v"(p0[2 * i]), "v"(p0[2 * i + 1]));
      asm("v_cvt_pk_bf16_f32 %0, %1, %2" : "=v"(pk1[i]) : "v"(p1[2 * i]), "v"(p1[2 * i + 1]));
    }
    bf16x8 pf[4];
#pragma unroll
    for (int kb = 0; kb < 4; kb++) {
      const unsigned* pk = (kb < 2) ? pk0 : pk1;
      int m = kb & 1;
      unsigned d0 = pk[4 * m + 0], d1 = pk[4 * m + 1];
      unsigned e0 = pk[4 * m + 2], e1 = pk[4 * m + 3];
      asm volatile("v_permlane32_swap_b32 %0, %1" : "+v"(d0), "+v"(e0));
      asm volatile("v_permlane32_swap_b32 %0, %1" : "+v"(d1), "+v"(e1));
      union { unsigned u[4]; bf16x8 v; } uu;
      uu.u[0] = d0; uu.u[1] = d1; uu.u[2] = e0; uu.u[3] = e1;
      pf[kb] = uu.v;
    }

    // ---- PV: O[q][d] += P · K ; lane holds d=lq(+32dblk), q rows per C-layout ----
#pragma unroll
    for (int kb = 0; kb < 4; kb++) {
      bf16x8 v0 = *reinterpret_cast<const bf16x8*>(KaB + pv_off[0][kb]);
      o0 = __builtin_amdgcn_mfma_f32_32x32x16_bf16(pf[kb], v0, o0, 0, 0, 0);
    }
#pragma unroll
    for (int kb = 0; kb < 4; kb++) {
      bf16x8 v1 = *reinterpret_cast<const bf16x8*>(KaB + pv_off[1][kb]);
      o1 = __builtin_amdgcn_mfma_f32_32x32x16_bf16(pf[kb], v1, o1, 0, 0, 0);
    }
    __syncthreads();
  }

  // ---- epilogue: divide by l (per q-row, via bpermute), store bf16 ----
  float linv = 1.0f / l_run;
#pragma unroll
  for (int r = 0; r < 16; r++) {
    int qr = (r & 3) + 8 * (r >> 2) + 4 * hi;
    float lv = __shfl(linv, qr);
    size_t grow = (size_t)(q0 + w * 32 + qr);
    att[grow * DIM + h * HD + lq] = f2b(o0[r] * lv);
    att[grow * DIM + h * HD + 32 + lq] = f2b(o1[r] * lv);
  }
}

extern "C" void kernel_launch(void* const* d_in, const int* in_sizes, int n_in,
                              void* d_out, int out_size, void* d_ws, size_t ws_size,
                              hipStream_t stream) {
  const float* x = (const float*)d_in[0];
  const float* w_qkv = (const float*)d_in[1];
  const float* w_out = (const float*)d_in[2];
  const float* b_out = (const float*)d_in[3];
  float* out = (float*)d_out;

  char* ws = (char*)d_ws;
  unsigned short* xb   = (unsigned short*)(ws);              // [4096][1024]   8 MB
  unsigned short* wqkT = (unsigned short*)(ws + 8388608);    // [2048][1024]   4 MB
  unsigned short* woT  = (unsigned short*)(ws + 12582912);   // [1024][1024]   2 MB
  unsigned short* qhb  = (unsigned short*)(ws + 14680064);   // [16][4096][64] 8 MB (scaled q)
  unsigned short* krm  = (unsigned short*)(ws + 23068672);   // [16][4096][64] 8 MB
  unsigned short* ktb  = (unsigned short*)(ws + 31457280);   // [16][64][4096] 8 MB
  unsigned short* attb = (unsigned short*)(ws + 39845888);   // [4096][1024]   8 MB

  k_cvt<<<(NT * DIM / 4 + 255) / 256, 256, 0, stream>>>((const float4*)x, (ushort4*)xb,
                                                        NT * DIM / 4);
  dim3 g1(2048 / 32, 1024 / 32);
  k_trans_w<<<g1, 256, 0, stream>>>(w_qkv, 3 * DIM, wqkT, DIM);
  dim3 g2(1024 / 32, 1024 / 32);
  k_trans_w<<<g2, 256, 0, stream>>>(w_out, DIM, woT, DIM);
  dim3 g3(2048 / 128, NT / 128);
  k_gemm<0><<<g3, 256, 0, stream>>>(xb, wqkT, qhb, krm, nullptr, nullptr);
  dim3 g4(NT / 64, NH);
  k_transK<<<g4, 256, 0, stream>>>(krm, ktb);
  k_attn<<<(NT / 128) * NH, 256, 0, stream>>>(qhb, krm, ktb, attb);
  dim3 g5(DIM / 128, NT / 128);
  k_gemm<1><<<g5, 256, 0, stream>>>(attb, woT, nullptr, nullptr, out, b_out);
}

// Round 5
// 181.614 us; speedup vs baseline: 1.3619x; 1.1564x over previous
//
#include <hip/hip_runtime.h>
#include <hip/hip_bf16.h>

#define NT 4096
#define DIM 1024
#define NH 16
#define HD 64

typedef __attribute__((ext_vector_type(8))) short bf16x8;
typedef __attribute__((ext_vector_type(4))) float f32x4;
typedef __attribute__((ext_vector_type(16))) float f32x16;

__device__ __forceinline__ unsigned short f2b(float f) {
  union { float f; unsigned u; } v; v.f = f;
  unsigned r = v.u + 0x7fffu + ((v.u >> 16) & 1u);
  return (unsigned short)(r >> 16);
}

// exp2 via the hardware TRANS op. Builtin (not naked asm) so the backend's
// hazard recognizer handles the TRANS->VALU wait state. Fallback: libm.
__device__ __forceinline__ float fexp2(float x) {
#if __has_builtin(__builtin_amdgcn_exp2f)
  return __builtin_amdgcn_exp2f(x);
#else
  return exp2f(x);
#endif
}

// ---------- 1) fp32 -> bf16 elementwise ----------
__global__ void k_cvt(const float4* __restrict__ src, ushort4* __restrict__ dst, int n4) {
  int i = blockIdx.x * blockDim.x + threadIdx.x;
  if (i >= n4) return;
  float4 v = src[i];
  ushort4 o;
  o.x = f2b(v.x); o.y = f2b(v.y); o.z = f2b(v.z); o.w = f2b(v.w);
  dst[i] = o;
}

// ---------- 2) transpose fp32 [1024][S] (cols [0,N)) -> bf16 [N][1024] ----------
__global__ __launch_bounds__(256) void k_trans_w(const float* __restrict__ src, int S,
                                                 unsigned short* __restrict__ dst, int Kdim) {
  __shared__ float tile[32][33];
  int j0 = blockIdx.x * 32, k0 = blockIdx.y * 32;
  int t = threadIdx.x;
  int c = t & 31, rq = t >> 5;
#pragma unroll
  for (int i = 0; i < 4; i++) {
    int r = rq + i * 8;
    tile[r][c] = src[(size_t)(k0 + r) * S + j0 + c];
  }
  __syncthreads();
#pragma unroll
  for (int i = 0; i < 4; i++) {
    int jr = rq + i * 8;
    dst[(size_t)(j0 + jr) * Kdim + k0 + c] = f2b(tile[c][jr]);
  }
}

// ---------- 3) bf16 MFMA GEMM, 128x128 tile, B given transposed [N][K] ----------
template <int EPI>
__global__ __launch_bounds__(256) void k_gemm(const unsigned short* __restrict__ A,
                                              const unsigned short* __restrict__ Bt,
                                              unsigned short* __restrict__ qh,
                                              unsigned short* __restrict__ krm,
                                              float* __restrict__ cout,
                                              const float* __restrict__ bias) {
  __shared__ unsigned short As[128][40];
  __shared__ unsigned short Bs[128][40];
  const int K = 1024;
  int m0 = blockIdx.y * 128, n0 = blockIdx.x * 128;
  int t = threadIdx.x;
  int w = t >> 6, l = t & 63;
  int wr = w >> 1, wc = w & 1;
  int lq = l & 15, lg = l >> 4;
  f32x4 zero = {0.f, 0.f, 0.f, 0.f};
  f32x4 acc[4][4];
#pragma unroll
  for (int i = 0; i < 4; i++)
#pragma unroll
    for (int j = 0; j < 4; j++) acc[i][j] = zero;

  for (int k0 = 0; k0 < K; k0 += 32) {
#pragma unroll
    for (int s = 0; s < 2; s++) {
      int slot = t + s * 256;
      int r = slot >> 2, c8 = (slot & 3) * 8;
      *reinterpret_cast<bf16x8*>(&As[r][c8]) =
          *reinterpret_cast<const bf16x8*>(A + (size_t)(m0 + r) * K + k0 + c8);
      *reinterpret_cast<bf16x8*>(&Bs[r][c8]) =
          *reinterpret_cast<const bf16x8*>(Bt + (size_t)(n0 + r) * K + k0 + c8);
    }
    __syncthreads();
    bf16x8 af[4], bf[4];
#pragma unroll
    for (int mi = 0; mi < 4; mi++)
      af[mi] = *reinterpret_cast<bf16x8*>(&As[wr * 64 + mi * 16 + lq][lg * 8]);
#pragma unroll
    for (int ni = 0; ni < 4; ni++)
      bf[ni] = *reinterpret_cast<bf16x8*>(&Bs[wc * 64 + ni * 16 + lq][lg * 8]);
#pragma unroll
    for (int mi = 0; mi < 4; mi++)
#pragma unroll
      for (int ni = 0; ni < 4; ni++)
        acc[mi][ni] =
            __builtin_amdgcn_mfma_f32_16x16x32_bf16(af[mi], bf[ni], acc[mi][ni], 0, 0, 0);
    __syncthreads();
  }
#pragma unroll
  for (int mi = 0; mi < 4; mi++) {
#pragma unroll
    for (int ni = 0; ni < 4; ni++) {
      int j = n0 + wc * 64 + ni * 16 + lq;
#pragma unroll
      for (int r = 0; r < 4; r++) {
        int row = m0 + wr * 64 + mi * 16 + lg * 4 + r;
        float v = acc[mi][ni][r];
        if (EPI == 0) {
          if (j < DIM) {
            // fold 1/8 and log2(e): softmax uses exp2 directly
            qh[((size_t)(j >> 6) << 18) + (size_t)row * HD + (j & 63)] =
                f2b(v * 0.18033688011112042f);
          } else {
            int jj = j - DIM;
            krm[((size_t)(jj >> 6) << 18) + (size_t)row * HD + (jj & 63)] = f2b(v);
          }
        } else {
          cout[(size_t)row * DIM + j] = v + bias[j];
        }
      }
    }
  }
}

// ---------- 4) per-head transpose K[h][n][64] -> Kt[h][64][4096] ----------
__global__ __launch_bounds__(256) void k_transK(const unsigned short* __restrict__ krm,
                                                unsigned short* __restrict__ kt) {
  __shared__ unsigned short tile[64][72];
  int h = blockIdx.y, n0 = blockIdx.x * 64;
  int t = threadIdx.x;
  const unsigned short* src = krm + (size_t)h * NT * HD;
#pragma unroll
  for (int s = 0; s < 2; s++) {
    int slot = t + s * 256;
    int r = slot >> 3, c8 = (slot & 7) * 8;
    *reinterpret_cast<bf16x8*>(&tile[r][c8]) =
        *reinterpret_cast<const bf16x8*>(src + (size_t)(n0 + r) * HD + c8);
  }
  __syncthreads();
  unsigned short* dst = kt + (size_t)h * HD * NT;
#pragma unroll
  for (int s = 0; s < 2; s++) {
    int slot = t + s * 256;
    int dd = slot & 63, c8 = (slot >> 6) * 8;
    bf16x8 vv;
#pragma unroll
    for (int i = 0; i < 8; i++) vv[i] = (short)tile[c8 + i][dd];
    *reinterpret_cast<bf16x8*>(dst + (size_t)dd * NT + n0 + c8) = vv;
  }
}

// ---------- 5) flash attention, V := K, 32x32 MFMA, in-register P ----------
// 4 waves x 32 q-rows = 128 q/block; KVBLK=64; scores already in log2 domain.
__global__ __launch_bounds__(256) void k_attn(const unsigned short* __restrict__ qh,
                                              const unsigned short* __restrict__ krm,
                                              const unsigned short* __restrict__ kt,
                                              unsigned short* __restrict__ att) {
  __shared__ __align__(16) unsigned char sbuf[2][16384];  // [Ka 8K | Ktl 8K] x dbuf

  // XCD swizzle: 512 blocks, xcd = hw&7 handles heads {2*xcd, 2*xcd+1}
  int hw = blockIdx.x;
  int xcd = hw & 7, idx = hw >> 3;
  int h = xcd * 2 + (idx >> 5);
  int q0 = (idx & 31) * 128;

  int t = threadIdx.x, w = t >> 6, l = t & 63;
  int lq = l & 31, hi = l >> 5;
  const unsigned char* Kb = (const unsigned char*)(krm + (size_t)h * NT * HD);
  const unsigned char* Tb = (const unsigned char*)(kt + (size_t)h * HD * NT);
  const unsigned short* Qb = qh + (size_t)h * NT * HD;

  int qrow = q0 + w * 32 + lq;
  bf16x8 qf[4];
#pragma unroll
  for (int ds = 0; ds < 4; ds++)
    qf[ds] = *reinterpret_cast<const bf16x8*>(Qb + (size_t)qrow * HD + ds * 16 + hi * 8);

  // precomputed swizzled LDS read offsets (tile-invariant)
  int swz = (lq & 7) << 4;
  int qk_off[2][4], pv_off[2][4];
#pragma unroll
  for (int kb2 = 0; kb2 < 2; kb2++)
#pragma unroll
    for (int ds = 0; ds < 4; ds++)
      qk_off[kb2][ds] = ((kb2 * 32 + lq) << 7) + ((32 * ds + 16 * hi) ^ swz);
#pragma unroll
  for (int dblk = 0; dblk < 2; dblk++)
#pragma unroll
    for (int kb = 0; kb < 4; kb++)
      pv_off[dblk][kb] = 8192 + ((dblk * 32 + lq) << 7) + ((32 * kb + 16 * hi) ^ swz);

  f32x16 o0, o1;
#pragma unroll
  for (int r = 0; r < 16; r++) { o0[r] = 0.f; o1[r] = 0.f; }
  float m_run = -3.0e38f, l_run = 0.f;

  auto STAGE = [&](int b, int kv0) {
    unsigned char* base = &sbuf[b][0];
#pragma unroll
    for (int i = 0; i < 4; i++) {
      int c = w * 4 + i;
      int o = c * 1024 + l * 16;
      const unsigned char* g;
      if (c < 8) {
        int row = o >> 7;
        int so = (o ^ ((row & 7) << 4)) & 127;
        g = Kb + (size_t)(kv0 + row) * 128 + so;
      } else {
        int oo = o - 8192;
        int row = oo >> 7;
        int so = (oo ^ ((row & 7) << 4)) & 127;
        g = Tb + (size_t)row * 8192 + (size_t)kv0 * 2 + so;
      }
      __builtin_amdgcn_global_load_lds(
          (const __attribute__((address_space(1))) unsigned int*)g,
          (__attribute__((address_space(3))) unsigned int*)(base + c * 1024), 16, 0, 0);
    }
  };

  STAGE(0, 0);
  __syncthreads();

  for (int tile = 0; tile < 64; tile++) {
    int cur = tile & 1;
    if (tile < 63) STAGE(cur ^ 1, (tile + 1) * 64);
    const unsigned char* KaB = &sbuf[cur][0];

    // ---- QK^T (swapped): S'[kv][q], lane holds q=lq, kv rows per C-layout ----
    f32x16 s0, s1;
#pragma unroll
    for (int r = 0; r < 16; r++) { s0[r] = 0.f; s1[r] = 0.f; }
#pragma unroll
    for (int ds = 0; ds < 4; ds++) {
      bf16x8 a0 = *reinterpret_cast<const bf16x8*>(KaB + qk_off[0][ds]);
      bf16x8 a1 = *reinterpret_cast<const bf16x8*>(KaB + qk_off[1][ds]);
      s0 = __builtin_amdgcn_mfma_f32_32x32x16_bf16(a0, qf[ds], s0, 0, 0, 0);
      s1 = __builtin_amdgcn_mfma_f32_32x32x16_bf16(a1, qf[ds], s1, 0, 0, 0);
    }

    // ---- online softmax (log2 domain), full row in-lane ----
    float pm = -3.0e38f;
#pragma unroll
    for (int r = 0; r < 16; r++) pm = fmaxf(pm, fmaxf(s0[r], s1[r]));
    pm = fmaxf(pm, __shfl_xor(pm, 32));
    if (__any(pm > m_run + 8.0f)) {
      float newm = fmaxf(m_run, pm);
      float al = fexp2(m_run - newm);
#pragma unroll
      for (int r = 0; r < 16; r++) {
        float av = __shfl(al, (r & 3) + 8 * (r >> 2) + 4 * hi);
        o0[r] *= av;
        o1[r] *= av;
      }
      l_run *= al;
      m_run = newm;
    }
    float p0[16], p1[16];
    float ps = 0.f;
#pragma unroll
    for (int r = 0; r < 16; r++) { p0[r] = fexp2(s0[r] - m_run); ps += p0[r]; }
#pragma unroll
    for (int r = 0; r < 16; r++) { p1[r] = fexp2(s1[r] - m_run); ps += p1[r]; }
    ps += __shfl_xor(ps, 32);
    l_run += ps;

    // ---- P -> bf16 PV A-fragments, fully in-register (cvt_pk + permlane32_swap) ----
    unsigned pk0[8], pk1[8];
#pragma unroll
    for (int i = 0; i < 8; i++) {
      asm("v_cvt_pk_bf16_f32 %0, %1, %2" : "=v"(pk0[i]) : "v"(p0[2 * i]), "v"(p0[2 * i + 1]));
      asm("v_cvt_pk_bf16_f32 %0, %1, %2" : "=v"(pk1[i]) : "v"(p1[2 * i]), "v"(p1[2 * i + 1]));
    }
    bf16x8 pf[4];
#pragma unroll
    for (int kb = 0; kb < 4; kb++) {
      const unsigned* pk = (kb < 2) ? pk0 : pk1;
      int m = kb & 1;
      unsigned d0 = pk[4 * m + 0], d1 = pk[4 * m + 1];
      unsigned e0 = pk[4 * m + 2], e1 = pk[4 * m + 3];
      asm volatile("v_permlane32_swap_b32 %0, %1" : "+v"(d0), "+v"(e0));
      asm volatile("v_permlane32_swap_b32 %0, %1" : "+v"(d1), "+v"(e1));
      union { unsigned u[4]; bf16x8 v; } uu;
      uu.u[0] = d0; uu.u[1] = d1; uu.u[2] = e0; uu.u[3] = e1;
      pf[kb] = uu.v;
    }

    // ---- PV: O[q][d] += P · K ; lane holds d=lq(+32dblk), q rows per C-layout ----
#pragma unroll
    for (int kb = 0; kb < 4; kb++) {
      bf16x8 v0 = *reinterpret_cast<const bf16x8*>(KaB + pv_off[0][kb]);
      o0 = __builtin_amdgcn_mfma_f32_32x32x16_bf16(pf[kb], v0, o0, 0, 0, 0);
    }
#pragma unroll
    for (int kb = 0; kb < 4; kb++) {
      bf16x8 v1 = *reinterpret_cast<const bf16x8*>(KaB + pv_off[1][kb]);
      o1 = __builtin_amdgcn_mfma_f32_32x32x16_bf16(pf[kb], v1, o1, 0, 0, 0);
    }
    __syncthreads();
  }

  // ---- epilogue: divide by l (per q-row), store bf16 ----
  float linv = 1.0f / l_run;
#pragma unroll
  for (int r = 0; r < 16; r++) {
    int qr = (r & 3) + 8 * (r >> 2) + 4 * hi;
    float lv = __shfl(linv, qr);
    size_t grow = (size_t)(q0 + w * 32 + qr);
    att[grow * DIM + h * HD + lq] = f2b(o0[r] * lv);
    att[grow * DIM + h * HD + 32 + lq] = f2b(o1[r] * lv);
  }
}

extern "C" void kernel_launch(void* const* d_in, const int* in_sizes, int n_in,
                              void* d_out, int out_size, void* d_ws, size_t ws_size,
                              hipStream_t stream) {
  const float* x = (const float*)d_in[0];
  const float* w_qkv = (const float*)d_in[1];
  const float* w_out = (const float*)d_in[2];
  const float* b_out = (const float*)d_in[3];
  float* out = (float*)d_out;

  char* ws = (char*)d_ws;
  unsigned short* xb   = (unsigned short*)(ws);              // [4096][1024]   8 MB
  unsigned short* wqkT = (unsigned short*)(ws + 8388608);    // [2048][1024]   4 MB
  unsigned short* woT  = (unsigned short*)(ws + 12582912);   // [1024][1024]   2 MB
  unsigned short* qhb  = (unsigned short*)(ws + 14680064);   // [16][4096][64] 8 MB (scaled q)
  unsigned short* krm  = (unsigned short*)(ws + 23068672);   // [16][4096][64] 8 MB
  unsigned short* ktb  = (unsigned short*)(ws + 31457280);   // [16][64][4096] 8 MB
  unsigned short* attb = (unsigned short*)(ws + 39845888);   // [4096][1024]   8 MB

  k_cvt<<<(NT * DIM / 4 + 255) / 256, 256, 0, stream>>>((const float4*)x, (ushort4*)xb,
                                                        NT * DIM / 4);
  dim3 g1(2048 / 32, 1024 / 32);
  k_trans_w<<<g1, 256, 0, stream>>>(w_qkv, 3 * DIM, wqkT, DIM);
  dim3 g2(1024 / 32, 1024 / 32);
  k_trans_w<<<g2, 256, 0, stream>>>(w_out, DIM, woT, DIM);
  dim3 g3(2048 / 128, NT / 128);
  k_gemm<0><<<g3, 256, 0, stream>>>(xb, wqkT, qhb, krm, nullptr, nullptr);
  dim3 g4(NT / 64, NH);
  k_transK<<<g4, 256, 0, stream>>>(krm, ktb);
  k_attn<<<(NT / 128) * NH, 256, 0, stream>>>(qhb, krm, ktb, attb);
  dim3 g5(DIM / 128, NT / 128);
  k_gemm<1><<<g5, 256, 0, stream>>>(attb, woT, nullptr, nullptr, out, b_out);
}